// Round 16
// baseline (201.563 us; speedup 1.0000x reference)
//
#include <hip/hip_runtime.h>
#include <hip/hip_bf16.h>

typedef __bf16 bf16;
typedef __bf16 bf16x8 __attribute__((ext_vector_type(8)));
typedef float f32x4 __attribute__((ext_vector_type(4)));

#define S_DIM 128
#define L_DIM 512
#define D_DIM 256
#define NQ    1024

// async global->LDS, 16B per lane; lds must be the wave-uniform base
__device__ __forceinline__ void gl16(void* lds, const void* g) {
  __builtin_amdgcn_global_load_lds((const __attribute__((address_space(1))) void*)g,
                                   (__attribute__((address_space(3))) void*)lds,
                                   16, 0, 0);
}

// ---------------- K0: pack weights to bf16, transposed to N-major ----------------
__global__ void pack_weights(const float* __restrict__ wq, const float* __restrict__ wk,
                             const float* __restrict__ wv, const float* __restrict__ wg,
                             const float* __restrict__ wo,
                             bf16* __restrict__ wcat_t, bf16* __restrict__ wo_t) {
  int idx = blockIdx.x * 256 + threadIdx.x;
  const int total1 = NQ * D_DIM; // WcatT [1024][256]
  if (idx < total1) {
    int j = idx >> 8;      // output column 0..1023
    int d = idx & 255;     // k index
    const float* w = (j < 256) ? wq : (j < 512) ? wk : (j < 768) ? wv : wg;
    wcat_t[idx] = (bf16)w[d * 256 + (j & 255)];
  } else {
    int i2 = idx - total1; // woT [256][256]: woT[d][hc] = wo[hc][d]
    if (i2 < D_DIM * D_DIM) {
      int dcol = i2 >> 8, k = i2 & 255;
      wo_t[i2] = (bf16)wo[k * 256 + dcol];
    }
  }
}

// ---------------- K1: LayerNorm -> x_ln2 (row = res*128 + s), dense writes --------
__global__ __launch_bounds__(256) void ln_kernel(const float* __restrict__ x,
                                                 const float* __restrict__ sc,
                                                 const float* __restrict__ bs,
                                                 bf16* __restrict__ y) {
  const int wid  = threadIdx.x >> 6;
  const int lane = threadIdx.x & 63;
  const int res  = blockIdx.x;
  const int s0   = blockIdx.y * 32;
  float4 scv = ((const float4*)sc)[lane];
  float4 bsv = ((const float4*)bs)[lane];
  #pragma unroll
  for (int it = 0; it < 8; ++it) {
    int s = s0 + it * 4 + wid;
    float4 v = ((const float4*)(x + ((size_t)s * 512 + res) * 256))[lane];
    float sum = v.x + v.y + v.z + v.w;
    #pragma unroll
    for (int m = 32; m; m >>= 1) sum += __shfl_xor(sum, m);
    float mu = sum * (1.0f / 256.0f);
    float dx = v.x - mu, dy = v.y - mu, dz = v.z - mu, dw = v.w - mu;
    float s2 = dx * dx + dy * dy + dz * dz + dw * dw;
    #pragma unroll
    for (int m = 32; m; m >>= 1) s2 += __shfl_xor(s2, m);
    float rs = rsqrtf(s2 * (1.0f / 256.0f) + 1e-5f);
    union { uint2 u; bf16 b[4]; } o;
    o.b[0] = (bf16)(dx * rs * scv.x + bsv.x);
    o.b[1] = (bf16)(dy * rs * scv.y + bsv.y);
    o.b[2] = (bf16)(dz * rs * scv.z + bsv.z);
    o.b[3] = (bf16)(dw * rs * scv.w + bsv.w);
    ((uint2*)y)[((size_t)res * 128 + s) * 64 + lane] = o.u;
  }
}

// ---------------- K2: FUSED QKVG-GEMM + attention, per residue -------------------
// Block = residue (512 blocks), 512 thr / 8 waves, wave = head.
// x_ln staged once (ONE barrier); all B-frags straight from wcat_t (L2-hot);
// per wave: K->regs (via 1KB scratch transpose), V->LDS V^T (direct from C-frags),
// G->regs (C-layout == PV O-layout -> register gating), then per q-strip:
// Q-GEMM -> QK^T -> in-reg softmax -> PV -> gate -> coalesced obuf store.
// LDS: xln 64K | vt 8x8K | pwb 8x2K | scr 8x1K = 152 KB -> 1 block/CU.
__global__ __launch_bounds__(512, 2) void qkvg_attn(const bf16* __restrict__ xln,
                                                    const bf16* __restrict__ wcat,
                                                    const float* __restrict__ bg,
                                                    bf16* __restrict__ obuf) {
  __shared__ __align__(16) char smem[155648];
  const int tid  = threadIdx.x;
  const int wid  = tid >> 6;
  const int lane = tid & 63;
  const int lrow = lane & 15;
  const int lkg  = lane >> 4;
  const int lk   = lkg * 8;
  const int rb   = lkg * 4;
  const int res  = blockIdx.x;
  const int h    = wid;

  char* xlds = smem;                        // [128 s][512 B] swz ^((s&7)<<4)
  char* vw   = smem + 65536 + wid * 8192;   // [32 c][128 t] bf16 swz ^((c&7)<<4)
  char* pwb  = smem + 131072 + wid * 2048;  // [16 r][64 c] bf16 swz ^((r&7)<<4)
  char* scr  = smem + 147456 + wid * 1024;  // [16 t][64 B] swz ^(((t>>2)&3)<<4)

  // ---- stage x_ln slab (contiguous 64 KB), pre-swizzled source ----
  {
    const char* xsrc = (const char*)(xln + (size_t)res * 128 * 256);
    #pragma unroll
    for (int p = 0; p < 8; ++p) {
      int chunk = p * 512 + tid;
      int row = chunk >> 5, slot = chunk & 31;
      gl16(xlds + (p * 512 + wid * 64) * 16, xsrc + row * 512 + ((slot ^ (row & 7)) * 16));
    }
  }
  __syncthreads();   // the ONLY block-wide barrier

  // A-frag from x_ln LDS: (strip st, kfrag kk) -> lane(row=st*16+lrow, k=kk*32+lk)
  #define LDA(st, kk) (*(const bf16x8*)(xlds + \
      ((((st) * 16 + lrow) * 512 + ((kk) * 32 + lk) * 2) ^ ((((st) * 16 + lrow) & 7) << 4))))

  const f32x4 z = {0.f, 0.f, 0.f, 0.f};
  bf16x8 kf[8];            // K B-frags for QK^T
  bf16  garr[8][2][4];     // gate values, C-frag layout (matches PV output)

  // ================= K =================
  {
    bf16x8 bw[2][8];
    #pragma unroll
    for (int cg = 0; cg < 2; ++cg)
      #pragma unroll
      for (int kk = 0; kk < 8; ++kk)
        bw[cg][kk] = *(const bf16x8*)(wcat + (size_t)(256 + h * 32 + cg * 16 + lrow) * 256 + kk * 32 + lk);
    #pragma unroll
    for (int st = 0; st < 8; ++st) {
      f32x4 c0 = z, c1 = z;
      #pragma unroll
      for (int kk = 0; kk < 8; ++kk) {
        bf16x8 a = LDA(st, kk);
        c0 = __builtin_amdgcn_mfma_f32_16x16x32_bf16(a, bw[0][kk], c0, 0, 0, 0);
        c1 = __builtin_amdgcn_mfma_f32_16x16x32_bf16(a, bw[1][kk], c1, 0, 0, 0);
      }
      // transpose через scratch: write C (t=rb+r, c=cg*16+lrow), read B-frag (t=lrow, c=lk..)
      #pragma unroll
      for (int r = 0; r < 4; ++r) {
        int t = rb + r;
        *(bf16*)(scr + (((t) * 64 + (lrow) * 2) ^ (((t >> 2) & 3) << 4))) = (bf16)c0[r];
        *(bf16*)(scr + (((t) * 64 + (16 + lrow) * 2) ^ (((t >> 2) & 3) << 4))) = (bf16)c1[r];
      }
      kf[st] = *(const bf16x8*)(scr + ((lrow * 64 + lkg * 16) ^ (((lrow >> 2) & 3) << 4)));
    }
  }

  // ================= V (direct transposed into vt) =================
  {
    bf16x8 bw[2][8];
    #pragma unroll
    for (int cg = 0; cg < 2; ++cg)
      #pragma unroll
      for (int kk = 0; kk < 8; ++kk)
        bw[cg][kk] = *(const bf16x8*)(wcat + (size_t)(512 + h * 32 + cg * 16 + lrow) * 256 + kk * 32 + lk);
    #pragma unroll
    for (int st = 0; st < 8; ++st) {
      f32x4 c0 = z, c1 = z;
      #pragma unroll
      for (int kk = 0; kk < 8; ++kk) {
        bf16x8 a = LDA(st, kk);
        c0 = __builtin_amdgcn_mfma_f32_16x16x32_bf16(a, bw[0][kk], c0, 0, 0, 0);
        c1 = __builtin_amdgcn_mfma_f32_16x16x32_bf16(a, bw[1][kk], c1, 0, 0, 0);
      }
      #pragma unroll
      for (int r = 0; r < 4; ++r) {
        int t = st * 16 + rb + r;
        int cA = lrow, cB = 16 + lrow;
        *(bf16*)(vw + ((cA * 256 + t * 2) ^ ((cA & 7) << 4))) = (bf16)c0[r];
        *(bf16*)(vw + ((cB * 256 + t * 2) ^ ((cB & 7) << 4))) = (bf16)c1[r];
      }
    }
  }

  // ================= G (keep in regs; layout matches PV O) =================
  {
    bf16x8 bw[2][8];
    #pragma unroll
    for (int cg = 0; cg < 2; ++cg)
      #pragma unroll
      for (int kk = 0; kk < 8; ++kk)
        bw[cg][kk] = *(const bf16x8*)(wcat + (size_t)(768 + h * 32 + cg * 16 + lrow) * 256 + kk * 32 + lk);
    float bg0 = bg[h * 32 + lrow];
    float bg1 = bg[h * 32 + 16 + lrow];
    #pragma unroll
    for (int st = 0; st < 8; ++st) {
      f32x4 c0 = z, c1 = z;
      #pragma unroll
      for (int kk = 0; kk < 8; ++kk) {
        bf16x8 a = LDA(st, kk);
        c0 = __builtin_amdgcn_mfma_f32_16x16x32_bf16(a, bw[0][kk], c0, 0, 0, 0);
        c1 = __builtin_amdgcn_mfma_f32_16x16x32_bf16(a, bw[1][kk], c1, 0, 0, 0);
      }
      #pragma unroll
      for (int r = 0; r < 4; ++r) {
        garr[st][0][r] = (bf16)(1.0f / (1.0f + __expf(-(c0[r] + bg0))));
        garr[st][1][r] = (bf16)(1.0f / (1.0f + __expf(-(c1[r] + bg1))));
      }
    }
  }

  // ================= Q + attention per strip =================
  {
    bf16x8 bw[2][8];
    #pragma unroll
    for (int cg = 0; cg < 2; ++cg)
      #pragma unroll
      for (int kk = 0; kk < 8; ++kk)
        bw[cg][kk] = *(const bf16x8*)(wcat + (size_t)(h * 32 + cg * 16 + lrow) * 256 + kk * 32 + lk);
    const float scale = 0.17677669529663687f; // 1/sqrt(32)

    for (int st = 0; st < 8; ++st) {
      // q strip GEMM
      f32x4 c0 = z, c1 = z;
      #pragma unroll
      for (int kk = 0; kk < 8; ++kk) {
        bf16x8 a = LDA(st, kk);
        c0 = __builtin_amdgcn_mfma_f32_16x16x32_bf16(a, bw[0][kk], c0, 0, 0, 0);
        c1 = __builtin_amdgcn_mfma_f32_16x16x32_bf16(a, bw[1][kk], c1, 0, 0, 0);
      }
      #pragma unroll
      for (int r = 0; r < 4; ++r) {
        int t = rb + r;
        *(bf16*)(scr + (((t) * 64 + (lrow) * 2) ^ (((t >> 2) & 3) << 4))) = (bf16)c0[r];
        *(bf16*)(scr + (((t) * 64 + (16 + lrow) * 2) ^ (((t >> 2) & 3) << 4))) = (bf16)c1[r];
      }
      bf16x8 qf = *(const bf16x8*)(scr + ((lrow * 64 + lkg * 16) ^ (((lrow >> 2) & 3) << 4)));

      // QK^T
      f32x4 sc[8];
      #pragma unroll
      for (int tt = 0; tt < 8; ++tt)
        sc[tt] = __builtin_amdgcn_mfma_f32_16x16x32_bf16(qf, kf[tt], z, 0, 0, 0);

      // softmax over t (in-lane 8 regs + 16-lane-group shuffles)
      #pragma unroll
      for (int r = 0; r < 4; ++r) {
        float m = sc[0][r];
        #pragma unroll
        for (int tc = 1; tc < 8; ++tc) m = fmaxf(m, sc[tc][r]);
        #pragma unroll
        for (int msk = 8; msk; msk >>= 1) m = fmaxf(m, __shfl_xor(m, msk));
        float pv[8], ssum = 0.f;
        #pragma unroll
        for (int tc = 0; tc < 8; ++tc) {
          float p = __expf((sc[tc][r] - m) * scale);
          pv[tc] = p; ssum += p;
        }
        #pragma unroll
        for (int msk = 8; msk; msk >>= 1) ssum += __shfl_xor(ssum, msk);
        float inv = 1.0f / ssum;
        #pragma unroll
        for (int tc = 0; tc < 8; ++tc) sc[tc][r] = pv[tc] * inv;
      }

      // PV through swizzled wave-private P buffer (two t-halves of 64)
      f32x4 oc[2] = {z, z};
      #pragma unroll
      for (int hf = 0; hf < 2; ++hf) {
        #pragma unroll
        for (int tc = 0; tc < 4; ++tc)
          #pragma unroll
          for (int r = 0; r < 4; ++r) {
            int row = rb + r, col = tc * 16 + lrow;
            *(bf16*)(pwb + ((row * 128 + col * 2) ^ ((row & 7) << 4))) = (bf16)sc[hf * 4 + tc][r];
          }
        #pragma unroll
        for (int kc = 0; kc < 2; ++kc) {
          bf16x8 pa = *(const bf16x8*)(pwb + ((lrow * 128 + (kc * 32 + lk) * 2) ^ ((lrow & 7) << 4)));
          #pragma unroll
          for (int ct = 0; ct < 2; ++ct) {
            int c = ct * 16 + lrow;
            bf16x8 bv = *(const bf16x8*)(vw + ((c * 256 + (hf * 64 + kc * 32 + lk) * 2) ^ ((c & 7) << 4)));
            oc[ct] = __builtin_amdgcn_mfma_f32_16x16x32_bf16(pa, bv, oc[ct], 0, 0, 0);
          }
        }
      }

      // gate in registers (same C-frag layout), transpose via pwb, coalesced store
      #pragma unroll
      for (int ct = 0; ct < 2; ++ct)
        #pragma unroll
        for (int r = 0; r < 4; ++r) {
          int row = rb + r, c = ct * 16 + lrow;
          float val = oc[ct][r] * (float)garr[st][ct][r];
          *(bf16*)(pwb + ((row * 128 + c * 2) ^ ((row & 7) << 4))) = (bf16)val;
        }
      {
        int row = lane >> 2, cb = lane & 3;
        uint4 o8 = *(const uint4*)(pwb + ((row * 128 + cb * 16) ^ ((row & 7) << 4)));
        *(uint4*)(obuf + ((size_t)res * 128 + st * 16 + row) * 256 + h * 32 + cb * 8) = o8;
      }
    }
  }
  #undef LDA
}

// ---------------- K3: output projection: obuf[65536][256] @ woT + bo -> out -------
// rows of obuf are (res*128 + s); out row = s*512 + res (remapped at store).
__device__ __forceinline__ bf16x8 lds_swz(const char* base, int row, int k) {
  return *(const bf16x8*)(base + (((row << 7) + (k << 1)) ^ ((row & 7) << 4)));
}

__global__ __launch_bounds__(256, 4) void gemm_proj(const bf16* __restrict__ A,
                                                    const bf16* __restrict__ Bt,
                                                    float* __restrict__ Cout,
                                                    const float* __restrict__ bias) {
  __shared__ __align__(16) bf16 smem[16384];
  char* As = (char*)smem;
  char* Bs = (char*)(smem + 8192);
  const int tid  = threadIdx.x;
  const int wid  = tid >> 6;
  const int lane = tid & 63;
  const int bid   = blockIdx.x;
  const int n_idx = (bid >> 3) & 1;
  const int m_idx = (bid & 7) | ((bid >> 4) << 3);
  const int m0 = m_idx * 128;
  const int n0 = n_idx * 128;
  const int lrow = lane & 15;
  const int lk   = (lane >> 4) * 8;
  const int wr = wid >> 1, wc = wid & 1;

  const int ln8 = lane >> 3;
  const int c8  = ((lane & 7) ^ ln8) * 8;

  const bf16* Arow = A  + (size_t)m0 * 256 + c8;
  const bf16* Brow = Bt + (size_t)n0 * 256 + c8;

  f32x4 acc[4][4] = {};

  #pragma unroll
  for (int ks = 0; ks < 4; ++ks) {
    const int k0 = ks * 64;
    #pragma unroll
    for (int t = 0; t < 4; ++t) {
      int chunk = wid * 4 + t;
      int r = chunk * 8 + ln8;
      gl16(As + chunk * 1024, Arow + (size_t)r * 256 + k0);
      gl16(Bs + chunk * 1024, Brow + (size_t)r * 256 + k0);
    }
    __syncthreads();
    #pragma unroll
    for (int kk = 0; kk < 64; kk += 32) {
      bf16x8 av[4], bv[4];
      #pragma unroll
      for (int i = 0; i < 4; ++i)
        av[i] = lds_swz(As, wr * 64 + i * 16 + lrow, kk + lk);
      #pragma unroll
      for (int j = 0; j < 4; ++j)
        bv[j] = lds_swz(Bs, wc * 64 + j * 16 + lrow, kk + lk);
      #pragma unroll
      for (int i = 0; i < 4; ++i)
        #pragma unroll
        for (int j = 0; j < 4; ++j)
          acc[i][j] = __builtin_amdgcn_mfma_f32_16x16x32_bf16(av[i], bv[j], acc[i][j], 0, 0, 0);
    }
    __syncthreads();
  }

  const int rb = (lane >> 4) * 4;
  const int xorv = rb << 2;
  float* smf = (float*)smem;
  float bov[4];
  #pragma unroll
  for (int j = 0; j < 4; ++j) bov[j] = bias[n0 + wc * 64 + j * 16 + lrow];
  #pragma unroll
  for (int half = 0; half < 2; ++half) {
    if (half) __syncthreads();
    #pragma unroll
    for (int i2 = 0; i2 < 2; ++i2) {
      int i = half * 2 + i2;
      #pragma unroll
      for (int j = 0; j < 4; ++j) {
        int col = wc * 64 + j * 16 + lrow;
        #pragma unroll
        for (int r = 0; r < 4; ++r) {
          int crow = wr * 32 + i2 * 16 + rb + r;
          smf[crow * 128 + (col ^ xorv)] = acc[i][j][r] + bov[j];
        }
      }
    }
    __syncthreads();
    #pragma unroll
    for (int p = 0; p < 8; ++p) {
      int ch = p * 256 + tid;
      int crow = ch >> 5, slot = (ch & 31) * 4;
      int rx = (crow & 12) << 2;
      int s_loc = (crow >> 5) * 64 + half * 32 + (crow & 31);
      *(uint4*)(Cout + ((size_t)s_loc * 512 + m_idx) * 256 + n0 + slot) =
          *(const uint4*)(smf + crow * 128 + (slot ^ rx));
    }
  }
}

// ---------------- launch ----------------
extern "C" void kernel_launch(void* const* d_in, const int* in_sizes, int n_in,
                              void* d_out, int out_size, void* d_ws, size_t ws_size,
                              hipStream_t stream) {
  const float* msa      = (const float*)d_in[0];
  const float* ln_scale = (const float*)d_in[1];
  const float* ln_bias  = (const float*)d_in[2];
  const float* wq       = (const float*)d_in[3];
  const float* wk       = (const float*)d_in[4];
  const float* wv       = (const float*)d_in[5];
  const float* wg       = (const float*)d_in[6];
  const float* bg       = (const float*)d_in[7];
  const float* wo       = (const float*)d_in[8];
  const float* bo       = (const float*)d_in[9];
  float* out = (float*)d_out;

  char* ws = (char*)d_ws;
  bf16* wcat_t = (bf16*)ws;                                  // 512 KB
  bf16* wo_t   = (bf16*)(ws + 524288);                       // 128 KB
  bf16* obuf   = (bf16*)(ws + 655360);                       // 32 MB gated o
  bf16* x_ln2  = (bf16*)(ws + 655360 + 33554432ULL);         // 32 MB (row = res*128+s)

  pack_weights<<<dim3(1280), dim3(256), 0, stream>>>(wq, wk, wv, wg, wo, wcat_t, wo_t);
  ln_kernel<<<dim3(512, 4), dim3(256), 0, stream>>>(msa, ln_scale, ln_bias, x_ln2);
  qkvg_attn<<<dim3(512), dim3(512), 0, stream>>>(x_ln2, wcat_t, bg, obuf);
  gemm_proj<<<dim3(1024), dim3(256), 0, stream>>>(obuf, wo_t, out, bo);
}